// Round 1
// baseline (5912.980 us; speedup 1.0000x reference)
//
#include <hip/hip_runtime.h>

#define NBINS 18
#define NB 2
#define NC 16
#define FP 30
#define FA 50
#define NS 20
#define NT 1024
#define TC 128          // t-chunk
#define PG 8            // p's per group
#define NPG 4           // p-groups (8,8,8,6)
#define AP 51           // a-columns incl. ones-column for counts

// Accumulation kernel: one workgroup per ((b,c,s), p-group).
// LDS acc[p][k][a] holds bin sums; column a==50 holds counts (ones staged).
template <bool DIRECT>
__global__ __launch_bounds__(256) void mi_accum(const float* __restrict__ pha,
                                                const float* __restrict__ amp,
                                                const float* __restrict__ cut,
                                                float* __restrict__ outp) {
    __shared__ float acc[PG * NBINS * AP];     // 29376 B
    __shared__ float ampch[TC * AP];           // 26112 B
    __shared__ unsigned char binch[PG * TC];   // 1024 B
    __shared__ float cuts[NBINS + 1];

    const int wg  = blockIdx.x;
    const int pg  = wg & (NPG - 1);
    const int bcs = wg >> 2;
    const int s   = bcs % NS;
    const int bc  = bcs / NS;          // b*C + c
    const int p0  = pg * PG;
    const int np  = (FP - p0) < PG ? (FP - p0) : PG;   // 8 or 6

    const int tid = threadIdx.x;
    if (tid < NBINS + 1) cuts[tid] = cut[tid];
    for (int i = tid; i < PG * NBINS * AP; i += 256) acc[i] = 0.f;

    const float* pha_bc = pha + (size_t)bc * FP * NS * NT + (size_t)s * NT;
    const float* amp_bc = amp + (size_t)bc * FA * NS * NT + (size_t)s * NT;

    for (int ch = 0; ch < NT / TC; ++ch) {
        const int t0 = ch * TC;
        __syncthreads();   // acc zero / previous chunk's readers done
        // ---- stage bins (u8) ----
        for (int i = tid; i < PG * TC; i += 256) {
            const int p = i >> 7;          // TC = 128
            const int t = i & (TC - 1);
            unsigned char bin = 0;
            if (p < np) {
                const float v = pha_bc[(size_t)(p0 + p) * NS * NT + t0 + t];
                int idx = 0;
                #pragma unroll
                for (int j = 0; j <= NBINS; ++j) idx += (cuts[j] < v) ? 1 : 0;
                int bb = idx - 1;
                bb = bb < 0 ? 0 : (bb > NBINS - 1 ? NBINS - 1 : bb);
                bin = (unsigned char)bb;
            }
            binch[i] = bin;
        }
        // ---- stage amp chunk + ones column; lds stride 51 (odd) => conflict-free ----
        for (int i = tid; i < AP * TC; i += 256) {
            const int a = i >> 7;
            const int t = i & (TC - 1);
            const float v = (a < FA) ? amp_bc[(size_t)a * NS * NT + t0 + t] : 1.0f;
            ampch[t * AP + a] = v;
        }
        __syncthreads();
        // ---- accumulate: wave w owns p = {w, w+4}; lanes = a (51 active) ----
        const int w = tid >> 6, l = tid & 63;
        if (l < AP) {
            const int pa = w, pb = w + 4;
            const bool hasA = pa < np, hasB = pb < np;
            float* accA = &acc[pa * NBINS * AP + l];
            float* accB = &acc[pb * NBINS * AP + l];
            const unsigned char* binA = &binch[pa * TC];
            const unsigned char* binB = &binch[pb * TC];
            #pragma unroll 4
            for (int t = 0; t < TC; ++t) {
                const float av = ampch[t * AP + l];
                if (hasA) { const int k = binA[t]; atomicAdd(&accA[k * AP], av); }
                if (hasB) { const int k = binB[t]; atomicAdd(&accB[k * AP], av); }
            }
        }
    }
    __syncthreads();
    // ---- epilogue: items (p, a) ----
    for (int item = tid; item < np * FA; item += 256) {
        const int p = item / FA;
        const int a = item - p * FA;
        float means[NBINS];
        float tot = 0.f;
        #pragma unroll
        for (int k = 0; k < NBINS; ++k) {
            const float sum = acc[(p * NBINS + k) * AP + a];
            const float cnt = acc[(p * NBINS + k) * AP + FA];
            const float m = sum / (cnt + 1e-9f);
            means[k] = m;
            tot += m;
        }
        const float den = tot + 1e-9f;
        float ent = 0.f;
        #pragma unroll
        for (int k = 0; k < NBINS; ++k) {
            const float pr = means[k] / den;
            ent += pr * logf(pr + 1e-9f);
        }
        const float l18 = logf(18.0f);
        const float mi = (l18 + ent) / l18;
        const size_t oi = (size_t)(bc * FP + p0 + p) * FA + a;
        if (DIRECT) {
            atomicAdd(&outp[oi], mi * (1.0f / NS));
        } else {
            outp[oi * NS + s] = mi;
        }
    }
}

__global__ void mi_reduce(const float* __restrict__ partial, float* __restrict__ out) {
    const int i = blockIdx.x * 256 + threadIdx.x;
    if (i < NB * NC * FP * FA) {
        const float* p = partial + (size_t)i * NS;
        float acc = 0.f;
        #pragma unroll
        for (int j = 0; j < NS; ++j) acc += p[j];
        out[i] = acc / (float)NS;
    }
}

extern "C" void kernel_launch(void* const* d_in, const int* in_sizes, int n_in,
                              void* d_out, int out_size, void* d_ws, size_t ws_size,
                              hipStream_t stream) {
    const float* pha = (const float*)d_in[0];
    const float* amp = (const float*)d_in[1];
    const float* cut = (const float*)d_in[2];
    float* out = (float*)d_out;

    const int nout = NB * NC * FP * FA;                  // 48000
    const size_t need = (size_t)nout * NS * sizeof(float); // 3.84 MB partials
    const dim3 grid(NB * NC * NS * NPG);                  // 2560

    if (ws_size >= need) {
        float* partial = (float*)d_ws;
        mi_accum<false><<<grid, 256, 0, stream>>>(pha, amp, cut, partial);
        mi_reduce<<<(nout + 255) / 256, 256, 0, stream>>>(partial, out);
    } else {
        hipMemsetAsync(d_out, 0, (size_t)nout * sizeof(float), stream);
        mi_accum<true><<<grid, 256, 0, stream>>>(pha, amp, cut, out);
    }
}

// Round 2
// 615.066 us; speedup vs baseline: 9.6136x; 9.6136x over previous
//
#include <hip/hip_runtime.h>
#include <math.h>

#define NBINS 18
#define NB 2
#define NC 16
#define FP 30
#define FA 50
#define NS 20
#define NT 1024
#define TC 64               // t-chunk (GEMM K-chunk)
#define PGSZ 15             // p's per block
#define NPG 2               // p-groups
#define MROWS 288           // padded M (PGSZ*NBINS = 270 -> 288)
#define NCOL 64             // padded N (50 a's + count col + pad)
#define ASTR 72             // Atile k-stride in bf16 elems (64 used + 8 pad)
#define BSTR 152            // Btile row stride bf16: [hi 72][lo 72][pad 8]
#define ATILE_B (MROWS * ASTR * 2)      // 41472 B
#define BTILE_B (NCOL * BSTR * 2)       // 19456 B
#define SMEM_B (ATILE_B + BTILE_B)      // 60928 B  (reused as fp32 acc[270][52] = 56160 B)
#define NTHR 384
#define ACCSTR 52

typedef __attribute__((ext_vector_type(8))) short bf16x8;
typedef __attribute__((ext_vector_type(4))) float f32x4;

__device__ inline unsigned short f2bf(float x) {
    unsigned int u = __builtin_bit_cast(unsigned int, x);
    unsigned int r = (u + 0x7FFFu + ((u >> 16) & 1u)) >> 16;   // RNE
    return (unsigned short)r;
}
__device__ inline float bf2f(unsigned short b) {
    unsigned int u = ((unsigned int)b) << 16;
    return __builtin_bit_cast(float, u);
}

// One block = (b*c*s batch, p-group of 15). GEMM: C[(p,k)][a] = sum_t onehot * amp.
template <bool DIRECT>
__global__ __launch_bounds__(NTHR, 3) void mi_mfma(const float* __restrict__ pha,
                                                   const float* __restrict__ amp,
                                                   const float* __restrict__ cut,
                                                   float* __restrict__ outp) {
    __shared__ __align__(16) char smem[SMEM_B];
    short* At = (short*)smem;                    // one-hot A tile [MROWS][ASTR]
    short* Bt = (short*)(smem + ATILE_B);        // amp hi/lo B tile [NCOL][BSTR]
    float* accs = (float*)smem;                  // epilogue reuse: [270][ACCSTR]

    const int bid = blockIdx.x;
    const int pg  = bid & 1;
    const int bcs = bid >> 1;
    const int s   = bcs % NS;
    const int bc  = bcs / NS;
    const int p0  = pg * PGSZ;

    const int tid  = threadIdx.x;
    const int lane = tid & 63;
    const int w    = tid >> 6;                   // wave 0..5
    const int l16  = lane & 15;
    const int quad = lane >> 4;

    // cutoffs: uniform -> scalar regs
    float cuts[NBINS + 1];
    #pragma unroll
    for (int j = 0; j <= NBINS; ++j) cuts[j] = cut[j];

    // zero both tiles once (A stays zero except scattered ones; B rows 51..63 stay zero)
    {
        int4* p4 = (int4*)smem;
        const int n4 = SMEM_B / 16;
        for (int i = tid; i < n4; i += NTHR) p4[i] = make_int4(0, 0, 0, 0);
    }
    __syncthreads();
    // ones column (n = 50): hi = 1.0 bf16, lo stays 0. Constant across chunks.
    if (tid < TC) Bt[FA * BSTR + tid] = (short)0x3F80;

    f32x4 acc[3][4];
    #pragma unroll
    for (int mt = 0; mt < 3; ++mt)
        #pragma unroll
        for (int nt = 0; nt < 4; ++nt)
            acc[mt][nt] = (f32x4){0.f, 0.f, 0.f, 0.f};

    int ahold[3];
    int nh = 0;

    for (int ch = 0; ch < NT / TC; ++ch) {
        const int t0 = ch * TC;
        // ---- build phase (writes; prev MFMA reads finished at loop-end barrier) ----
        // clear previous chunk's ones (each A position owned by exactly one thread)
        for (int r = 0; r < nh; ++r) At[ahold[r]] = 0;
        nh = 0;
        // scatter new ones: exact searchsorted(left) binning via 19 compares
        for (int i = tid; i < PGSZ * TC; i += NTHR) {
            const int p  = i >> 6;
            const int tl = i & 63;
            const float v = pha[((size_t)(bc * FP + p0 + p) * NS + s) * NT + t0 + tl];
            int cnt = 0;
            #pragma unroll
            for (int j = 0; j <= NBINS; ++j) cnt += (cuts[j] < v) ? 1 : 0;
            int k = cnt - 1;
            k = k < 0 ? 0 : (k > NBINS - 1 ? NBINS - 1 : k);
            const int addr = (p * NBINS + k) * ASTR + tl;
            At[addr] = (short)0x3F80;            // bf16 1.0
            ahold[nh++] = addr;
        }
        // stage B: amp hi/lo split, t-pairs packed as one b32 write each
        for (int i = tid; i < FA * (TC / 2); i += NTHR) {
            const int a  = i >> 5;
            const int tp = i & 31;
            const float2 v2 = *(const float2*)&amp[((size_t)(bc * FA + a) * NS + s) * NT + t0 + 2 * tp];
            const unsigned short h0 = f2bf(v2.x), h1 = f2bf(v2.y);
            const unsigned short l0 = f2bf(v2.x - bf2f(h0));
            const unsigned short l1 = f2bf(v2.y - bf2f(h1));
            *(unsigned int*)&Bt[a * BSTR + 2 * tp]      = (unsigned int)h0 | ((unsigned int)h1 << 16);
            *(unsigned int*)&Bt[a * BSTR + 72 + 2 * tp] = (unsigned int)l0 | ((unsigned int)l1 << 16);
        }
        __syncthreads();
        // ---- MFMA phase: wave w owns rows [w*48, w*48+48), all 4 n-tiles ----
        #pragma unroll
        for (int ks = 0; ks < 2; ++ks) {
            const int k0 = ks * 32 + quad * 8;
            bf16x8 af[3];
            #pragma unroll
            for (int mt = 0; mt < 3; ++mt)
                af[mt] = *(const bf16x8*)&At[(w * 48 + mt * 16 + l16) * ASTR + k0];
            bf16x8 bh[4], bl[4];
            #pragma unroll
            for (int nt = 0; nt < 4; ++nt) {
                bh[nt] = *(const bf16x8*)&Bt[(nt * 16 + l16) * BSTR + k0];
                bl[nt] = *(const bf16x8*)&Bt[(nt * 16 + l16) * BSTR + 72 + k0];
            }
            #pragma unroll
            for (int mt = 0; mt < 3; ++mt)
                #pragma unroll
                for (int nt = 0; nt < 4; ++nt)
                    acc[mt][nt] = __builtin_amdgcn_mfma_f32_16x16x32_bf16(af[mt], bh[nt], acc[mt][nt], 0, 0, 0);
            #pragma unroll
            for (int mt = 0; mt < 3; ++mt)
                #pragma unroll
                for (int nt = 0; nt < 4; ++nt)
                    acc[mt][nt] = __builtin_amdgcn_mfma_f32_16x16x32_bf16(af[mt], bl[nt], acc[mt][nt], 0, 0, 0);
        }
        __syncthreads();
    }

    // ---- dump C to LDS (reusing tile space): C/D layout col=lane&15, row=quad*4+reg ----
    #pragma unroll
    for (int mt = 0; mt < 3; ++mt) {
        const int row0 = w * 48 + mt * 16 + quad * 4;
        #pragma unroll
        for (int nt = 0; nt < 4; ++nt) {
            const int col = nt * 16 + l16;
            if (col <= FA) {
                #pragma unroll
                for (int r = 0; r < 4; ++r) {
                    const int row = row0 + r;
                    if (row < PGSZ * NBINS) accs[row * ACCSTR + col] = acc[mt][nt][r];
                }
            }
        }
    }
    __syncthreads();

    // ---- epilogue: per (p_local, a) — identical math to verified R1 ----
    const float l18 = logf(18.0f);
    for (int item = tid; item < PGSZ * FA; item += NTHR) {
        const int pl = item / FA;
        const int a  = item - pl * FA;
        float means[NBINS];
        float tot = 0.f;
        #pragma unroll
        for (int k = 0; k < NBINS; ++k) {
            const float sum  = accs[(pl * NBINS + k) * ACCSTR + a];
            const float cnt2 = accs[(pl * NBINS + k) * ACCSTR + FA];
            const float m = sum / (cnt2 + 1e-9f);
            means[k] = m;
            tot += m;
        }
        const float den = tot + 1e-9f;
        float ent = 0.f;
        #pragma unroll
        for (int k = 0; k < NBINS; ++k) {
            const float pr = means[k] / den;
            ent += pr * logf(pr + 1e-9f);
        }
        const float mi = (l18 + ent) / l18;
        const size_t oi = (size_t)(bc * FP + p0 + pl) * FA + a;
        if (DIRECT) {
            atomicAdd(&outp[oi], mi * (1.0f / NS));
        } else {
            outp[oi * NS + s] = mi;
        }
    }
}

__global__ void mi_reduce(const float* __restrict__ partial, float* __restrict__ out) {
    const int i = blockIdx.x * 256 + threadIdx.x;
    if (i < NB * NC * FP * FA) {
        const float* p = partial + (size_t)i * NS;
        float acc = 0.f;
        #pragma unroll
        for (int j = 0; j < NS; ++j) acc += p[j];
        out[i] = acc / (float)NS;
    }
}

extern "C" void kernel_launch(void* const* d_in, const int* in_sizes, int n_in,
                              void* d_out, int out_size, void* d_ws, size_t ws_size,
                              hipStream_t stream) {
    const float* pha = (const float*)d_in[0];
    const float* amp = (const float*)d_in[1];
    const float* cut = (const float*)d_in[2];
    float* out = (float*)d_out;

    const int nout = NB * NC * FP * FA;                      // 48000
    const size_t need = (size_t)nout * NS * sizeof(float);   // 3.84 MB
    const dim3 grid(NB * NC * NS * NPG);                     // 1280

    if (ws_size >= need) {
        float* partial = (float*)d_ws;
        mi_mfma<false><<<grid, NTHR, 0, stream>>>(pha, amp, cut, partial);
        mi_reduce<<<(nout + 255) / 256, 256, 0, stream>>>(partial, out);
    } else {
        hipMemsetAsync(d_out, 0, (size_t)nout * sizeof(float), stream);
        mi_mfma<true><<<grid, NTHR, 0, stream>>>(pha, amp, cut, out);
    }
}

// Round 4
// 443.030 us; speedup vs baseline: 13.3467x; 1.3883x over previous
//
#include <hip/hip_runtime.h>
#include <math.h>

#define NBINS 18
#define NB 2
#define NC 16
#define FP 30
#define FA 50
#define NS 20
#define NT 1024
#define TS 128              // t per staging chunk
#define NCH (NT / TS)       // 8
#define PGSZ 15             // p's per block
#define NTHR 384
#define BSTR 136            // shorts per B row (128 + 8 pad) = 272 B, 16B-aligned
#define BINSTR 136          // bytes per bins row (128 + 8 pad)
#define ACCW 52

#define BIN_OFF (2 * 64 * BSTR * 2)       // 34816
#define SMEM_B (BIN_OFF + PGSZ * BINSTR)  // 36856

typedef __attribute__((ext_vector_type(8))) short bf16x8;
typedef __attribute__((ext_vector_type(4))) float f32x4;

__device__ inline float u2f(unsigned int u) { return __builtin_bit_cast(float, u); }
__device__ inline unsigned short f2bf(float x) {
    unsigned int u = __builtin_bit_cast(unsigned int, x);
    unsigned int r = (u + 0x7FFFu + ((u >> 16) & 1u)) >> 16;   // RNE
    return (unsigned short)r;
}

template <bool DIRECT>
__global__ __launch_bounds__(NTHR) void mi_mfma(const float* __restrict__ pha,
                                                const float* __restrict__ amp,
                                                const float* __restrict__ cut,
                                                float* __restrict__ outp) {
    __shared__ __align__(16) char smem[SMEM_B];
    short* Bh = (short*)smem;
    float* accs = (float*)smem;           // epilogue reuse

    // block decode: pairs (g, g+8) share bcs's amp slice on the same XCD
    const int g   = blockIdx.x;
    const int pg  = (g >> 3) & 1;
    const int bcs = (g >> 4) * 8 + (g & 7);
    const int s   = bcs % NS;
    const int bc  = bcs / NS;
    const int p0  = pg * PGSZ;

    const int tid  = threadIdx.x;
    const int lane = tid & 63;
    const int w    = tid >> 6;            // 0..5
    const int l16  = lane & 15;
    const int quad = lane >> 4;

    // interior cutoffs only (cuts[0]=-pi, cuts[18]=pi never change the clamped bin)
    float cuts[NBINS];
    #pragma unroll
    for (int j = 1; j <= 17; ++j) cuts[j] = cut[j];

    // per-lane one-hot row params: rows w*48 + mt*16 + l16
    int pm[3]; unsigned kx[3];
    #pragma unroll
    for (int mt = 0; mt < 3; ++mt) {
        const int row = w * 48 + mt * 16 + l16;
        const int valid = row < PGSZ * NBINS;
        const int p = valid ? (row / NBINS) : (PGSZ - 1);
        const int kb = valid ? (row - p * NBINS) : 31;   // 31: never matches (bins<=17), no byte-carry
        pm[mt] = p;
        kx[mt] = (unsigned)kb * 0x01010101u;
    }

    // count column (a=50): hi=1.0 bf16, lo=0 — written once, never overwritten
    for (int t = tid; t < TS; t += NTHR) {
        Bh[FA * BSTR + t] = (short)0x3F80;
        Bh[64 * BSTR + FA * BSTR + t] = 0;
    }

    f32x4 acc[3][4];
    #pragma unroll
    for (int mt = 0; mt < 3; ++mt)
        #pragma unroll
        for (int nt = 0; nt < 4; ++nt) acc[mt][nt] = (f32x4){0.f, 0.f, 0.f, 0.f};

    const size_t phabase0 = ((size_t)(bc * FP + p0) * NS + s) * NT;
    const size_t ampbase0 = ((size_t)bc * FA * NS + s) * NT;

    for (int ch = 0; ch < NCH; ++ch) {
        __syncthreads();   // prev chunk's MFMA reads done (iter 0: count-col visible)
        // ---- stage bins: 1920 = 5*384 exact, compile-time trips ----
        const size_t phabase = phabase0 + ch * TS;
        #pragma unroll
        for (int r = 0; r < 5; ++r) {
            const int i = tid + r * NTHR;
            const int p = i >> 7, t = i & (TS - 1);
            const float v = pha[phabase + (size_t)p * (NS * NT) + t];
            int b = 0;
            #pragma unroll
            for (int j = 1; j <= 17; ++j) b += (cuts[j] < v) ? 1 : 0;
            smem[BIN_OFF + p * BINSTR + t] = (char)b;
        }
        // ---- stage amp hi/lo bf16 planes: 1600 float4, 5 guarded trips ----
        const size_t ampbase = ampbase0 + ch * TS;
        #pragma unroll
        for (int r = 0; r < 5; ++r) {
            const int i = tid + r * NTHR;
            if (i < FA * (TS / 4)) {
                const int a_ = i >> 5, tq = i & 31;
                const float4 v4 = *(const float4*)(amp + ampbase + (size_t)a_ * (NS * NT) + tq * 4);
                const unsigned short h0 = f2bf(v4.x), h1 = f2bf(v4.y);
                const unsigned short h2 = f2bf(v4.z), h3 = f2bf(v4.w);
                const unsigned short q0 = f2bf(v4.x - u2f((unsigned)h0 << 16));
                const unsigned short q1 = f2bf(v4.y - u2f((unsigned)h1 << 16));
                const unsigned short q2 = f2bf(v4.z - u2f((unsigned)h2 << 16));
                const unsigned short q3 = f2bf(v4.w - u2f((unsigned)h3 << 16));
                short* dst = Bh + a_ * BSTR + tq * 4;
                uint2 hv; hv.x = (unsigned)h0 | ((unsigned)h1 << 16); hv.y = (unsigned)h2 | ((unsigned)h3 << 16);
                uint2 lv; lv.x = (unsigned)q0 | ((unsigned)q1 << 16); lv.y = (unsigned)q2 | ((unsigned)q3 << 16);
                *(uint2*)dst = hv;
                *(uint2*)(dst + 64 * BSTR) = lv;
            }
        }
        __syncthreads();
        // ---- MFMA phase: 4 K-steps of 32 ----
        #pragma unroll
        for (int ks = 0; ks < 4; ++ks) {
            // A fragments: one-hot built in registers from bins (broadcast b64 reads)
            bf16x8 af[3];
            #pragma unroll
            for (int mt = 0; mt < 3; ++mt) {
                const uint2 d = *(const uint2*)(smem + BIN_OFF + pm[mt] * BINSTR + ks * 32 + quad * 8);
                const unsigned x0 = d.x ^ kx[mt];
                const unsigned x1 = d.y ^ kx[mt];
                const unsigned f0 = ~(x0 + 0x7F7F7F7Fu) & 0x80808080u;  // exact: bytes <= 31
                const unsigned f1 = ~(x1 + 0x7F7F7F7Fu) & 0x80808080u;
                uint4 a4;
                a4.x = (f0 & 0x80u) * 0x7Fu + ((f0 >> 8) & 0x80u) * 0x7F0000u;   // 0x80*0x7F=0x3F80
                a4.y = ((f0 >> 16) & 0x80u) * 0x7Fu + (f0 >> 24) * 0x7F0000u;
                a4.z = (f1 & 0x80u) * 0x7Fu + ((f1 >> 8) & 0x80u) * 0x7F0000u;
                a4.w = ((f1 >> 16) & 0x80u) * 0x7Fu + (f1 >> 24) * 0x7F0000u;
                af[mt] = __builtin_bit_cast(bf16x8, a4);
            }
            bf16x8 bh[4], bl[4];
            #pragma unroll
            for (int nt = 0; nt < 4; ++nt) {
                const short* bp = Bh + (nt * 16 + l16) * BSTR + ks * 32 + quad * 8;
                bh[nt] = *(const bf16x8*)bp;
                bl[nt] = *(const bf16x8*)(bp + 64 * BSTR);
            }
            #pragma unroll
            for (int mt = 0; mt < 3; ++mt)
                #pragma unroll
                for (int nt = 0; nt < 4; ++nt)
                    acc[mt][nt] = __builtin_amdgcn_mfma_f32_16x16x32_bf16(af[mt], bh[nt], acc[mt][nt], 0, 0, 0);
            #pragma unroll
            for (int mt = 0; mt < 3; ++mt)
                #pragma unroll
                for (int nt = 0; nt < 4; ++nt)
                    acc[mt][nt] = __builtin_amdgcn_mfma_f32_16x16x32_bf16(af[mt], bl[nt], acc[mt][nt], 0, 0, 0);
        }
    }
    __syncthreads();   // last MFMA reads done before smem reuse

    // ---- epilogue: 3 phases of 5 p's (90 rows) through reused LDS ----
    const float ln18 = 2.8903717578961645f;
    const float inv_ln18 = 0.34598234401512115f;
    #pragma unroll 1
    for (int ph = 0; ph < 3; ++ph) {
        const int rlo = ph * 90, rhi = rlo + 90;
        // dump C fragments in range (C/D layout: col=lane&15, row=quad*4+reg)
        #pragma unroll
        for (int mt = 0; mt < 3; ++mt) {
            #pragma unroll
            for (int nt = 0; nt < 4; ++nt) {
                const int col = nt * 16 + l16;
                if (col <= FA) {
                    #pragma unroll
                    for (int r2 = 0; r2 < 4; ++r2) {
                        const int row = w * 48 + mt * 16 + quad * 4 + r2;
                        if (row >= rlo && row < rhi)
                            accs[(row - rlo) * ACCW + col] = acc[mt][nt][r2];
                    }
                }
            }
        }
        __syncthreads();
        if (tid < 5 * FA) {
            const int pidx = tid / FA;
            const int a = tid - pidx * FA;
            float means[NBINS];
            float tot = 0.f;
            #pragma unroll
            for (int k = 0; k < NBINS; ++k) {
                const float sum = accs[(pidx * NBINS + k) * ACCW + a];
                const float cnt = accs[(pidx * NBINS + k) * ACCW + FA];
                const float m = sum / (cnt + 1e-9f);
                means[k] = m;
                tot += m;
            }
            const float rden = 1.0f / (tot + 1e-9f);
            float ent = 0.f;
            #pragma unroll
            for (int k = 0; k < NBINS; ++k) {
                const float pr = means[k] * rden;
                ent += pr * logf(pr + 1e-9f);
            }
            const float mi = (ln18 + ent) * inv_ln18;
            const int p = ph * 5 + pidx;
            const int oi = (bc * FP + p0 + p) * FA + a;
            if (DIRECT) {
                atomicAdd(&outp[oi], mi * (1.0f / NS));
            } else {
                outp[(size_t)s * (NB * NC * FP * FA) + oi] = mi;   // s-major: kernel2 coalesced
            }
        }
        __syncthreads();
    }
}

__global__ void mi_reduce(const float* __restrict__ partial, float* __restrict__ out) {
    const int i = blockIdx.x * 256 + threadIdx.x;
    const int n = NB * NC * FP * FA;
    if (i < n) {
        float acc = 0.f;
        #pragma unroll
        for (int j = 0; j < NS; ++j) acc += partial[(size_t)j * n + i];
        out[i] = acc * (1.0f / NS);
    }
}

extern "C" void kernel_launch(void* const* d_in, const int* in_sizes, int n_in,
                              void* d_out, int out_size, void* d_ws, size_t ws_size,
                              hipStream_t stream) {
    const float* pha = (const float*)d_in[0];
    const float* amp = (const float*)d_in[1];
    const float* cut = (const float*)d_in[2];
    float* out = (float*)d_out;

    const int nout = NB * NC * FP * FA;                      // 48000
    const size_t need = (size_t)nout * NS * sizeof(float);   // 3.84 MB
    const dim3 grid(NB * NC * NS * 2);                       // 1280

    if (ws_size >= need) {
        float* partial = (float*)d_ws;
        mi_mfma<false><<<grid, NTHR, 0, stream>>>(pha, amp, cut, partial);
        mi_reduce<<<(nout + 255) / 256, 256, 0, stream>>>(partial, out);
    } else {
        hipMemsetAsync(d_out, 0, (size_t)nout * sizeof(float), stream);
        mi_mfma<true><<<grid, NTHR, 0, stream>>>(pha, amp, cut, out);
    }
}